// Round 10
// baseline (256.064 us; speedup 1.0000x reference)
//
#include <hip/hip_runtime.h>
#include <float.h>

#define KTOP 32
#define BCAP 512           // per-segment bucket capacity (pre-cmask E[331]@thr2.05, ~10 sigma)
#define SENT_U32 0xFF7F0000u   // bf16-rounds to largest finite negative
#define VCLAMP 3.0e38f
// scores ~ N(0,1); P(s>=2.05)=2.02% -> pre-cmask E=331 (sigma 18, cap 512 = 10sig);
// post-cmask E=165 (sigma 12.8, >=KTOP at 10sig). Violations -> exact radix fallback.
#define STHRESH 2.05f

__device__ __forceinline__ unsigned int f2u(float f){
  unsigned int u = __float_as_uint(f);
  return (u & 0x80000000u) ? ~u : (u | 0x80000000u);
}

// =================== KB: all segment bounds (1025 parallel binary searches) ===================
__global__ void k_bounds(const int* __restrict__ batch, int* __restrict__ bounds,
                         int E, int NG)
{
  int t = blockIdx.x * blockDim.x + threadIdx.x;
  if (t > NG) return;
  int lo = 0, hi = E;
  while (lo < hi){
    int mid = (lo + hi) >> 1;
    if (batch[mid] < t) lo = mid + 1; else hi = mid;
  }
  bounds[t] = lo;
}

// =================== K1: sentinel fill (proven ~16us, ~4.3 TB/s) ===================
__global__ void __launch_bounds__(256, 8)
k_fill(float* __restrict__ out, int E)
{
  const float SENT = __uint_as_float(SENT_U32);
  const float4 sv = make_float4(SENT, SENT, SENT, SENT);
  float4* out4 = (float4*)out;
  int n4 = E >> 2;
  int stride = gridDim.x * blockDim.x;
  for (int q = blockIdx.x * blockDim.x + threadIdx.x; q < n4; q += stride)
    out4[q] = sv;
  for (int i = (n4 << 2) + blockIdx.x * blockDim.x + threadIdx.x; i < E; i += stride)
    out[i] = SENT;
}

// =================== KA: per-segment score stream + stash -> global bucket ===================
// The isolated phase-A measurement: reads scores only; writes ~1.7 MB bucket.
__global__ void __launch_bounds__(512, 4)
k_scan(const float* __restrict__ scores, const int* __restrict__ bounds,
       int* __restrict__ gcnt, uint2* __restrict__ bucket, int NG)
{
  __shared__ unsigned int st_u[BCAP];
  __shared__ int st_i[BCAP];
  __shared__ int scnt;
  int tid = threadIdx.x, g = blockIdx.x;
  if (tid == 0) scnt = 0;
  __syncthreads();
  int s = bounds[g], e = bounds[g + 1];
  int s4 = (s + 3) & ~3; if (s4 > e) s4 = e;
  int e4 = e & ~3;       if (e4 < s4) e4 = s4;
  const float4* sc4 = (const float4*)scores;

  auto proc4 = [&](float4 a, int bidx){   // proven r5/r6 aggregated stash
    int h = (a.x >= STHRESH ? 1 : 0) | (a.y >= STHRESH ? 2 : 0)
          | (a.z >= STHRESH ? 4 : 0) | (a.w >= STHRESH ? 8 : 0);
    if (h){
      int sl = atomicAdd(&scnt, __popc(h));
      if (h & 1){ if (sl < BCAP){ st_u[sl] = f2u(a.x); st_i[sl] = bidx;     } sl++; }
      if (h & 2){ if (sl < BCAP){ st_u[sl] = f2u(a.y); st_i[sl] = bidx + 1; } sl++; }
      if (h & 4){ if (sl < BCAP){ st_u[sl] = f2u(a.z); st_i[sl] = bidx + 2; } sl++; }
      if (h & 8){ if (sl < BCAP){ st_u[sl] = f2u(a.w); st_i[sl] = bidx + 3; } }
    }
  };
  auto st1 = [&](float sc, int idx){
    if (sc >= STHRESH){
      int sl = atomicAdd(&scnt, 1);
      if (sl < BCAP){ st_u[sl] = f2u(sc); st_i[sl] = idx; }
    }
  };
  {
    int i = s + tid;  if (i < s4) st1(scores[i], i);
    int j = e4 + tid; if (j < e)  st1(scores[j], j);
    int q  = (s4 >> 2) + tid;
    int qe = (e4 >> 2);
    for (; q + 3 * 512 < qe; q += 4 * 512){
      float4 a0 = sc4[q];
      float4 a1 = sc4[q +     512];
      float4 a2 = sc4[q + 2 * 512];
      float4 a3 = sc4[q + 3 * 512];
      proc4(a0, q << 2);
      proc4(a1, (q +     512) << 2);
      proc4(a2, (q + 2 * 512) << 2);
      proc4(a3, (q + 3 * 512) << 2);
    }
    for (; q < qe; q += 512){
      float4 a = sc4[q];
      proc4(a, q << 2);
    }
  }
  __syncthreads();
  int n = scnt;
  if (tid == 0) gcnt[g] = n;              // >BCAP signals fallback in KC
  int m = n < BCAP ? n : BCAP;
  for (int t = tid; t < m; t += 512)      // atomic-free bulk push (own segment)
    bucket[g * BCAP + t] = make_uint2(st_u[t], (unsigned)st_i[t]);
}

// ---------------- fallback helpers (exact radix select, 256-thread blocks) ----------------
__device__ int suffix_total(int* hist, int NB, int* gsum, int tid){
  int GS = NB >> 8;
  if (tid < 256){
    int p = 0, base = tid * GS;
    for (int j = 0; j < GS; ++j) p += hist[base + j];
    gsum[tid] = p;
  }
  __syncthreads();
  for (int d = 1; d < 256; d <<= 1){
    int v = 0;
    if (tid < 256) v = (tid + d < 256) ? gsum[tid + d] : 0;
    __syncthreads();
    if (tid < 256) gsum[tid] += v;
    __syncthreads();
  }
  return gsum[0];
}

__device__ int find_bin(int* hist, int NB, int* gsum, int R, int* s2, int tid,
                        int* above_out){
  int GS = NB >> 8;
  if (tid < 256){
    int St  = gsum[tid];
    int St1 = (tid < 255) ? gsum[tid + 1] : 0;
    if (R > St1 && R <= St) s2[0] = tid;
  }
  __syncthreads();
  if (tid == 0){
    int G = s2[0];
    int above = (G < 255) ? gsum[G + 1] : 0;
    int b = (G + 1) * GS - 1;
    for (; b > G * GS; --b){
      int h = hist[b];
      if (above + h >= R) break;
      above += h;
    }
    s2[0] = b; s2[1] = above;
  }
  __syncthreads();
  int bin = s2[0];
  *above_out = s2[1];
  __syncthreads();
  return bin;
}

// =================== KC: bucket -> cmask -> exact rank -> LSE -> scatter ===================
__global__ void __launch_bounds__(256, 8)
k_select2(const float* __restrict__ logits,
          const float* __restrict__ scores,
          const float* __restrict__ stop_logits,
          const int* __restrict__ cmask,
          const int* __restrict__ bounds,
          const int* __restrict__ gcnt,
          const uint2* __restrict__ bucket,
          float* __restrict__ out, int NG)
{
  __shared__ int hist[2048];        // fallback only
  __shared__ int gsum[256];
  __shared__ int s2[2];
  __shared__ unsigned int bin_u[BCAP];
  __shared__ int bin_i[BCAP];
  __shared__ int ab_i[KTOP];
  __shared__ int vidx[KTOP];
  __shared__ float vlog[KTOP];
  __shared__ int cnt_bin, cnt_ab, vcnt;
  __shared__ float sh_logden;

  int tid = threadIdx.x, g = blockIdx.x;
  if (tid == 0){ cnt_bin = 0; cnt_ab = 0; vcnt = 0; }
  __syncthreads();

  int n = gcnt[g];
  bool ovf = (n > BCAP);
  if (!ovf){
    // batched scattered cmask resolve over the ~331 bucket entries
    for (int t = tid; t < n; t += 256){
      uint2 ent = bucket[g * BCAP + t];
      if (cmask[(int)ent.y]){
        int sl = atomicAdd(&cnt_bin, 1);
        bin_u[sl] = ent.x; bin_i[sl] = (int)ent.y;   // sl < n <= BCAP
      }
    }
  }
  __syncthreads();
  int S = cnt_bin;

  if (!ovf && S >= KTOP){
    // ---- FAST PATH (exact): all candidates with score>=THR are in bin; S>=32
    // => top-32 subset. Rank by (u desc, idx asc) — reference tie-break.
    for (int jj = tid; jj < S; jj += 256){
      unsigned long long kj = ((unsigned long long)bin_u[jj] << 32)
                            | (unsigned long long)(unsigned)(~(unsigned)bin_i[jj]);
      int rank = 0;
      for (int k = 0; k < S; ++k){
        unsigned long long kk = ((unsigned long long)bin_u[k] << 32)
                              | (unsigned long long)(unsigned)(~(unsigned)bin_i[k]);
        rank += (kk > kj) ? 1 : 0;
      }
      if (rank < KTOP){
        int sl = atomicAdd(&vcnt, 1);
        if (sl < KTOP) vidx[sl] = bin_i[jj];
      }
    }
  } else {
    // ---- FALLBACK (exact, rare): full radix with dense scan; bounds from ws ----
    int s = bounds[g], e = bounds[g + 1];
    int s4 = (s + 3) & ~3; if (s4 > e) s4 = e;
    int e4 = e & ~3;       if (e4 < s4) e4 = s4;
    const float4* sc4 = (const float4*)scores;
    auto scan_sc = [&](auto&& fn){
      int i = s + tid;  if (i < s4) fn(scores[i], i);
      int j = e4 + tid; if (j < e)  fn(scores[j], j);
      for (int q = (s4 >> 2) + tid, qe = (e4 >> 2); q < qe; q += 256){
        float4 sc = sc4[q];
        int base = q << 2;
        fn(sc.x, base);     fn(sc.y, base + 1);
        fn(sc.z, base + 2); fn(sc.w, base + 3);
      }
    };
    auto is_cand = [&](int idx) -> bool { return cmask[idx] != 0; };

    for (int b = tid; b < 2048; b += 256) hist[b] = 0;
    if (tid == 0){ cnt_bin = 0; cnt_ab = 0; }
    __syncthreads();
    scan_sc([&](float sc, int idx){
      if (is_cand(idx)) atomicAdd(&hist[f2u(sc) >> 21], 1);
    });
    __syncthreads();
    int T = suffix_total(hist, 2048, gsum, tid);
    bool sel = (T > KTOP);
    unsigned int prefix = 0; int pshift = 32; int R = KTOP;
    if (sel){
      int above;
      int b1 = find_bin(hist, 2048, gsum, R, s2, tid, &above);
      R -= above; prefix = (unsigned)b1; pshift = 21;
      int hcnt = hist[b1];
      __syncthreads();
      if (hcnt > BCAP){                       // refine bits [20:10]
        for (int b = tid; b < 2048; b += 256) hist[b] = 0;
        __syncthreads();
        scan_sc([&](float sc, int idx){
          unsigned u = f2u(sc);
          if ((u >> 21) == prefix && is_cand(idx))
            atomicAdd(&hist[(u >> 10) & 0x7FFu], 1);
        });
        __syncthreads();
        suffix_total(hist, 2048, gsum, tid);
        int b2 = find_bin(hist, 2048, gsum, R, s2, tid, &above);
        R -= above; prefix = (prefix << 11) | (unsigned)b2; pshift = 10;
        hcnt = hist[b2];
        __syncthreads();
        if (hcnt > BCAP){                     // final bits [9:0]
          for (int b = tid; b < 1024; b += 256) hist[b] = 0;
          __syncthreads();
          scan_sc([&](float sc, int idx){
            unsigned u = f2u(sc);
            if ((u >> 10) == prefix && is_cand(idx))
              atomicAdd(&hist[u & 0x3FFu], 1);
          });
          __syncthreads();
          suffix_total(hist, 1024, gsum, tid);
          int b3 = find_bin(hist, 1024, gsum, R, s2, tid, &above);
          R -= above; prefix = (prefix << 10) | (unsigned)b3; pshift = 0;
          __syncthreads();
        }
      }
      scan_sc([&](float sc, int idx){
        unsigned u = f2u(sc);
        unsigned hp = (pshift < 32) ? (u >> pshift) : 0u;
        if (hp >= prefix){
          if (is_cand(idx)){
            if (hp == prefix){
              int sl = atomicAdd(&cnt_bin, 1);
              if (sl < BCAP){ bin_u[sl] = u; bin_i[sl] = idx; }
            } else {
              int sl = atomicAdd(&cnt_ab, 1);
              if (sl < KTOP) ab_i[sl] = idx;
            }
          }
        }
      });
      __syncthreads();
      int bn = min(cnt_bin, BCAP);
      for (int jj = tid; jj < bn; jj += 256){
        unsigned long long kj = ((unsigned long long)bin_u[jj] << 32)
                              | (unsigned long long)(unsigned)(~(unsigned)bin_i[jj]);
        int rank = 0;
        for (int k = 0; k < bn; ++k){
          unsigned long long kk2 = ((unsigned long long)bin_u[k] << 32)
                                 | (unsigned long long)(unsigned)(~(unsigned)bin_i[k]);
          rank += (kk2 > kj) ? 1 : 0;
        }
        if (rank < R){
          int sl = atomicAdd(&vcnt, 1);
          if (sl < KTOP) vidx[sl] = bin_i[jj];
        }
      }
      int na = min(cnt_ab, KTOP);
      for (int jj = tid; jj < na; jj += 256){
        int sl = atomicAdd(&vcnt, 1);
        if (sl < KTOP) vidx[sl] = ab_i[jj];
      }
    } else {
      scan_sc([&](float sc, int idx){
        (void)sc;
        if (is_cand(idx)){
          int sl = atomicAdd(&vcnt, 1);
          if (sl < KTOP) vidx[sl] = idx;
        }
      });
    }
  }
  __syncthreads();

  // ---- LSE over the <=32 valid logits ----
  int c = min(vcnt, KTOP);
  if (tid < c) vlog[tid] = logits[vidx[tid]];
  __syncthreads();
  if (tid < 64){
    float v = (tid < c) ? vlog[tid] : -FLT_MAX;
    float m = v;
    #pragma unroll
    for (int d = 32; d; d >>= 1) m = fmaxf(m, __shfl_xor(m, d));
    float ex = (tid < c) ? expf(v - m) : 0.f;
    #pragma unroll
    for (int d = 32; d; d >>= 1) ex += __shfl_xor(ex, d);
    if (tid == 0){
      float stop = stop_logits[g];              // TEMP == 1.0
      float logden;
      if (c == 0){
        logden = stop;
      } else {
        float lse = logf(fmaxf(ex, FLT_EPSILON)) + m;   // eps clamp per reference
        float mx = fmaxf(lse, stop);
        float dd = fabsf(lse - stop);
        logden = mx + log1pf(expf(-dd));
      }
      sh_logden = logden;
    }
  }
  __syncthreads();

  if (tid < c){
    float val = vlog[tid] - sh_logden;
    if (!(val >= -VCLAMP)) val = -VCLAMP;       // flushes NaN too
    if (val > VCLAMP)      val =  VCLAMP;
    out[vidx[tid]] = val;
  }
}

// =================== monolith fallback (only if workspace too small) ===================
__global__ void __launch_bounds__(512, 4)
fused_mono(const float* __restrict__ logits,
           const float* __restrict__ scores,
           const float* __restrict__ stop_logits,
           const int* __restrict__ batch,
           const int* __restrict__ cmask,
           float* __restrict__ out, int E, int NG)
{
  __shared__ int hist[2048];
  __shared__ int gsum[256];
  __shared__ int s2[2];
  __shared__ int sbounds[2];
  __shared__ unsigned int st_u[BCAP];
  __shared__ int st_i[BCAP];
  __shared__ int ab_i[KTOP];
  __shared__ int vidx[KTOP];
  __shared__ float vlog[KTOP];
  __shared__ int scnt, cnt_ab, vcnt;
  __shared__ float sh_logden;

  int tid = threadIdx.x, g = blockIdx.x;
  if (tid < 2){
    int target = g + tid;
    int lo = 0, hi = E;
    while (lo < hi){
      int mid = (lo + hi) >> 1;
      if (batch[mid] < target) lo = mid + 1; else hi = mid;
    }
    sbounds[tid] = lo;
  }
  if (tid == 0){ scnt = 0; cnt_ab = 0; vcnt = 0; }
  __syncthreads();
  int s = sbounds[0], e = sbounds[1];
  int s4 = (s + 3) & ~3; if (s4 > e) s4 = e;
  int e4 = e & ~3;       if (e4 < s4) e4 = s4;
  const float4* sc4 = (const float4*)scores;
  const float SENT = __uint_as_float(SENT_U32);
  const float4 sv = make_float4(SENT, SENT, SENT, SENT);
  float4* out4 = (float4*)out;

  auto p1 = [&](float sc, int idx){
    if (sc >= STHRESH){
      if (cmask[idx]){
        int sl = atomicAdd(&scnt, 1);
        if (sl < BCAP){ st_u[sl] = f2u(sc); st_i[sl] = idx; }
      }
    }
  };
  {
    int i = s + tid;  if (i < s4){ p1(scores[i], i); out[i] = SENT; }
    int j = e4 + tid; if (j < e) { p1(scores[j], j); out[j] = SENT; }
    for (int q = (s4 >> 2) + tid, qe = (e4 >> 2); q < qe; q += 512){
      float4 sc = sc4[q];
      out4[q] = sv;
      int base = q << 2;
      p1(sc.x, base);     p1(sc.y, base + 1);
      p1(sc.z, base + 2); p1(sc.w, base + 3);
    }
  }
  __syncthreads();

  int S = scnt;
  if (S >= KTOP && S <= BCAP){
    for (int jj = tid; jj < S; jj += 512){
      unsigned long long kj = ((unsigned long long)st_u[jj] << 32)
                            | (unsigned long long)(unsigned)(~(unsigned)st_i[jj]);
      int rank = 0;
      for (int k = 0; k < S; ++k){
        unsigned long long kk = ((unsigned long long)st_u[k] << 32)
                              | (unsigned long long)(unsigned)(~(unsigned)st_i[k]);
        rank += (kk > kj) ? 1 : 0;
      }
      if (rank < KTOP){
        int sl = atomicAdd(&vcnt, 1);
        if (sl < KTOP) vidx[sl] = st_i[jj];
      }
    }
  } else {
    auto scan_sc = [&](auto&& fn){
      int i = s + tid;  if (i < s4) fn(scores[i], i);
      int j = e4 + tid; if (j < e)  fn(scores[j], j);
      for (int q = (s4 >> 2) + tid, qe = (e4 >> 2); q < qe; q += 512){
        float4 sc = sc4[q];
        int base = q << 2;
        fn(sc.x, base);     fn(sc.y, base + 1);
        fn(sc.z, base + 2); fn(sc.w, base + 3);
      }
    };
    auto is_cand = [&](int idx) -> bool { return cmask[idx] != 0; };
    for (int b = tid; b < 2048; b += 512) hist[b] = 0;
    if (tid == 0){ scnt = 0; cnt_ab = 0; }
    __syncthreads();
    scan_sc([&](float sc, int idx){
      if (is_cand(idx)) atomicAdd(&hist[f2u(sc) >> 21], 1);
    });
    __syncthreads();
    int T = suffix_total(hist, 2048, gsum, tid);
    bool sel = (T > KTOP);
    unsigned int prefix = 0; int pshift = 32; int R = KTOP;
    if (sel){
      int above;
      int b1 = find_bin(hist, 2048, gsum, R, s2, tid, &above);
      R -= above; prefix = (unsigned)b1; pshift = 21;
      __syncthreads();
      scan_sc([&](float sc, int idx){
        unsigned u = f2u(sc);
        unsigned hp = (u >> pshift);
        if (hp >= prefix && is_cand(idx)){
          if (hp == prefix){
            int sl = atomicAdd(&scnt, 1);
            if (sl < BCAP){ st_u[sl] = u; st_i[sl] = idx; }
          } else {
            int sl = atomicAdd(&cnt_ab, 1);
            if (sl < KTOP) ab_i[sl] = idx;
          }
        }
      });
      __syncthreads();
      int bn = min(scnt, BCAP);
      for (int jj = tid; jj < bn; jj += 512){
        unsigned long long kj = ((unsigned long long)st_u[jj] << 32)
                              | (unsigned long long)(unsigned)(~(unsigned)st_i[jj]);
        int rank = 0;
        for (int k = 0; k < bn; ++k){
          unsigned long long kk2 = ((unsigned long long)st_u[k] << 32)
                                 | (unsigned long long)(unsigned)(~(unsigned)st_i[k]);
          rank += (kk2 > kj) ? 1 : 0;
        }
        if (rank < R){
          int sl = atomicAdd(&vcnt, 1);
          if (sl < KTOP) vidx[sl] = st_i[jj];
        }
      }
      int na = min(cnt_ab, KTOP);
      for (int jj = tid; jj < na; jj += 512){
        int sl = atomicAdd(&vcnt, 1);
        if (sl < KTOP) vidx[sl] = ab_i[jj];
      }
    } else {
      scan_sc([&](float sc, int idx){
        (void)sc;
        if (is_cand(idx)){
          int sl = atomicAdd(&vcnt, 1);
          if (sl < KTOP) vidx[sl] = idx;
        }
      });
    }
  }
  __syncthreads();
  int c = min(vcnt, KTOP);
  if (tid < c) vlog[tid] = logits[vidx[tid]];
  __syncthreads();
  if (tid < 64){
    float v = (tid < c) ? vlog[tid] : -FLT_MAX;
    float m = v;
    #pragma unroll
    for (int d = 32; d; d >>= 1) m = fmaxf(m, __shfl_xor(m, d));
    float ex = (tid < c) ? expf(v - m) : 0.f;
    #pragma unroll
    for (int d = 32; d; d >>= 1) ex += __shfl_xor(ex, d);
    if (tid == 0){
      float stop = stop_logits[g];
      float logden;
      if (c == 0) logden = stop;
      else {
        float lse = logf(fmaxf(ex, FLT_EPSILON)) + m;
        float mx = fmaxf(lse, stop);
        float dd = fabsf(lse - stop);
        logden = mx + log1pf(expf(-dd));
      }
      sh_logden = logden;
    }
  }
  __syncthreads();
  if (tid < c){
    float val = vlog[tid] - sh_logden;
    if (!(val >= -VCLAMP)) val = -VCLAMP;
    if (val > VCLAMP)      val =  VCLAMP;
    out[vidx[tid]] = val;
  }
}

extern "C" void kernel_launch(void* const* d_in, const int* in_sizes, int n_in,
                              void* d_out, int out_size, void* d_ws, size_t ws_size,
                              hipStream_t stream){
  const float* edge_logits = (const float*)d_in[0];
  const float* edge_scores = (const float*)d_in[1];
  const float* stop_logits = (const float*)d_in[2];
  const int*   edge_batch  = (const int*)d_in[3];
  const int*   cmask       = (const int*)d_in[4];
  int E  = in_sizes[0];
  int NG = in_sizes[2];
  float* out = (float*)d_out;

  size_t boundsB = (((size_t)NG + 1) * sizeof(int) + 255) & ~(size_t)255;
  size_t gcntB   = ((size_t)NG * sizeof(int) + 255) & ~(size_t)255;
  size_t need    = boundsB + gcntB + (size_t)NG * BCAP * sizeof(uint2);

  if (d_ws != nullptr && ws_size >= need){
    char* ws = (char*)d_ws;
    int*   bounds = (int*)ws;
    int*   gcnt   = (int*)(ws + boundsB);
    uint2* bucket = (uint2*)(ws + boundsB + gcntB);
    int nb = (NG + 1 + 511) / 512;
    hipLaunchKernelGGL(k_bounds, dim3(nb), dim3(512), 0, stream,
                       edge_batch, bounds, E, NG);
    hipLaunchKernelGGL(k_fill, dim3(2048), dim3(256), 0, stream, out, E);
    hipLaunchKernelGGL(k_scan, dim3(NG), dim3(512), 0, stream,
                       edge_scores, bounds, gcnt, bucket, NG);
    hipLaunchKernelGGL(k_select2, dim3(NG), dim3(256), 0, stream,
                       edge_logits, edge_scores, stop_logits, cmask,
                       bounds, gcnt, bucket, out, NG);
  } else {
    hipLaunchKernelGGL(fused_mono, dim3(NG), dim3(512), 0, stream,
                       edge_logits, edge_scores, stop_logits, edge_batch, cmask,
                       out, E, NG);
  }
}

// Round 11
// 236.892 us; speedup vs baseline: 1.0809x; 1.0809x over previous
//
#include <hip/hip_runtime.h>
#include <float.h>

#define TPB   256
#define SLOTS 12           // per-thread LDS stash slots; lambda=1.46 hits/thread,
                           // P(overflow anywhere) ~ 1e-3 per launch -> exact fallback
#define KTOP  32
#define BCAP  512          // block bin capacity (pre-cmask E[373] @ thr2.0, ~7 sigma)
#define SENT_U32 0xFF7F0000u   // bf16-rounds to largest finite negative
#define VCLAMP 3.0e38f
#define STHRESH 2.0f       // P(s>=2.0)=2.28%; per-segment pre-cmask E=373, post E=187

__device__ __forceinline__ unsigned int f2u(float f){
  unsigned int u = __float_as_uint(f);
  return (u & 0x80000000u) ? ~u : (u | 0x80000000u);
}

// ---------------- fallback helpers (exact radix select) ----------------
__device__ int suffix_total(int* hist, int NB, int* gsum, int tid){
  int GS = NB >> 8;
  if (tid < 256){
    int p = 0, base = tid * GS;
    for (int j = 0; j < GS; ++j) p += hist[base + j];
    gsum[tid] = p;
  }
  __syncthreads();
  for (int d = 1; d < 256; d <<= 1){
    int v = 0;
    if (tid < 256) v = (tid + d < 256) ? gsum[tid + d] : 0;
    __syncthreads();
    if (tid < 256) gsum[tid] += v;
    __syncthreads();
  }
  return gsum[0];
}

__device__ int find_bin(int* hist, int NB, int* gsum, int R, int* s2, int tid,
                        int* above_out){
  int GS = NB >> 8;
  if (tid < 256){
    int St  = gsum[tid];
    int St1 = (tid < 255) ? gsum[tid + 1] : 0;
    if (R > St1 && R <= St) s2[0] = tid;   // unique writer (gsum non-increasing)
  }
  __syncthreads();
  if (tid == 0){
    int G = s2[0];
    int above = (G < 255) ? gsum[G + 1] : 0;
    int b = (G + 1) * GS - 1;
    for (; b > G * GS; --b){
      int h = hist[b];
      if (above + h >= R) break;
      above += h;
    }
    s2[0] = b; s2[1] = above;
  }
  __syncthreads();
  int bin = s2[0];
  *above_out = s2[1];
  __syncthreads();
  return bin;
}

__global__ void __launch_bounds__(TPB)
fused_kernel(const float* __restrict__ logits,
             const float* __restrict__ scores,
             const float* __restrict__ stop_logits,
             const int* __restrict__ batch,
             const int* __restrict__ cmask,
             float* __restrict__ out, int E, int NG)
{
  // su/si: per-thread slot stash during the stream (NO atomics in hot loop).
  // After compaction they are dead and get reused: su -> hist (fallback) /
  // survivor keys (fast path), si -> survivor indices.
  __shared__ unsigned int su[TPB * SLOTS];   // 12 KB
  __shared__ int          si[TPB * SLOTS];   // 12 KB
  __shared__ unsigned int bin_u[BCAP];       // 2 KB
  __shared__ int          bin_i[BCAP];       // 2 KB
  __shared__ int gsum[256];
  __shared__ int s2[2];
  __shared__ int sbounds[2];
  __shared__ int srch[2];
  __shared__ int ab_i[KTOP];
  __shared__ int vidx[KTOP];
  __shared__ float vlog[KTOP];
  __shared__ int scnt, cnt2, cnt_ab, vcnt, ovfflag;
  __shared__ float sh_logden;

  int tid = threadIdx.x;
  int g = blockIdx.x;

  if (tid == 0){ scnt = 0; cnt2 = 0; cnt_ab = 0; vcnt = 0; ovfflag = 0; }

  // ---- segment bounds: cooperative 128-ary search (2 groups of 128) ----
  {
    int grp = tid >> 7;            // 0: lower_bound(g); 1: lower_bound(g+1)
    int lt  = tid & 127;
    int target = g + grp;
    int lo = 0, hi = E;            // invariant: batch[lo-1] < target <= batch[hi]
    for (int round = 0; round < 3; ++round){
      if (lt == 0) srch[grp] = 0;
      __syncthreads();
      int width = hi - lo;
      int pred = 0;
      if (width > 128){
        long long w = width;
        int q = lo + (int)((w * (long long)lt) >> 7);   // q_0 = lo, all q < hi
        pred = (batch[q] < target) ? 1 : 0;
      }
      unsigned long long bal = __ballot(pred);
      if ((tid & 63) == 0) atomicAdd(&srch[grp], __popcll(bal));
      __syncthreads();
      if (width > 128){
        long long w = width;
        int c = srch[grp];         // preds are a prefix (batch sorted)
        int nlo = (c > 0)   ? lo + (int)((w * (long long)(c - 1)) >> 7) + 1 : lo;
        int nhi = (c < 128) ? lo + (int)((w * (long long)c) >> 7)          : hi;
        lo = nlo; hi = nhi;
      }
      __syncthreads();
    }
    if (lt == 0) srch[grp] = 0;
    __syncthreads();
    int width = hi - lo;           // <= 9 after 3 rounds
    int pred = (lt < width) ? ((batch[lo + lt] < target) ? 1 : 0) : 0;
    unsigned long long bal = __ballot(pred);
    if ((tid & 63) == 0) atomicAdd(&srch[grp], __popcll(bal));
    __syncthreads();
    if (lt == 0) sbounds[grp] = lo + srch[grp];
    __syncthreads();
  }
  int s = sbounds[0], e = sbounds[1];

  int s4 = (s + 3) & ~3; if (s4 > e) s4 = e;
  int e4 = e & ~3;       if (e4 < s4) e4 = s4;
  const float4* sc4 = (const float4*)scores;
  const float SENT = __uint_as_float(SENT_U32);
  const float4 sv = make_float4(SENT, SENT, SENT, SENT);
  float4* out4 = (float4*)out;

  // ---- phase A: stream + sentinel fill + PRIVATE slot stash.
  // Hot loop has NO atomics, NO ballots, NO shared counters: predicated plain
  // LDS stores to thread-owned slots + a register counter. Overflow -> exact
  // fallback (flag checked later).
  int cnt = 0;
  int sbase = tid * SLOTS;
  auto stash = [&](float v, int idx){
    if (v >= STHRESH){
      if (cnt < SLOTS){ su[sbase + cnt] = f2u(v); si[sbase + cnt] = idx; }
      cnt++;
    }
  };
  {
    int i = s + tid;  if (i < s4){ stash(scores[i], i); out[i] = SENT; }
    int j = e4 + tid; if (j < e) { stash(scores[j], j); out[j] = SENT; }
    int q  = (s4 >> 2) + tid;
    int qe = (e4 >> 2);
    for (; q + 3 * TPB < qe; q += 4 * TPB){
      float4 a0 = sc4[q];
      float4 a1 = sc4[q +     TPB];
      float4 a2 = sc4[q + 2 * TPB];
      float4 a3 = sc4[q + 3 * TPB];
      out4[q]           = sv;
      out4[q +     TPB] = sv;
      out4[q + 2 * TPB] = sv;
      out4[q + 3 * TPB] = sv;
      int b0 = q << 2, b1 = (q + TPB) << 2, b2 = (q + 2 * TPB) << 2, b3 = (q + 3 * TPB) << 2;
      stash(a0.x, b0);     stash(a0.y, b0 + 1); stash(a0.z, b0 + 2); stash(a0.w, b0 + 3);
      stash(a1.x, b1);     stash(a1.y, b1 + 1); stash(a1.z, b1 + 2); stash(a1.w, b1 + 3);
      stash(a2.x, b2);     stash(a2.y, b2 + 1); stash(a2.z, b2 + 2); stash(a2.w, b2 + 3);
      stash(a3.x, b3);     stash(a3.y, b3 + 1); stash(a3.z, b3 + 2); stash(a3.w, b3 + 3);
    }
    for (; q < qe; q += TPB){
      float4 a = sc4[q];
      out4[q] = sv;
      int b0 = q << 2;
      stash(a.x, b0);     stash(a.y, b0 + 1);
      stash(a.z, b0 + 2); stash(a.w, b0 + 3);
    }
  }
  // ---- compaction: ONE atomic per thread (post-stream), slots -> bin ----
  if (cnt > SLOTS) ovfflag = 1;              // plain store, any-writer sets
  int myc = cnt < SLOTS ? cnt : SLOTS;
  __syncthreads();                            // slots fully written
  if (myc > 0){
    int base = atomicAdd(&scnt, myc);
    for (int k = 0; k < myc; ++k){
      int sl = base + k;
      if (sl < BCAP){ bin_u[sl] = su[sbase + k]; bin_i[sl] = si[sbase + k]; }
      else ovfflag = 1;
    }
  }
  __syncthreads();
  int total = scnt; if (total > BCAP) total = BCAP;

  // ---- phase B: batched cmask resolve, bin -> survivor arrays (reuse su/si) ----
  unsigned int* sv_u = su;                    // slots dead; reuse as survivors
  int*          sv_i = si;
  bool ovf = (ovfflag != 0);
  if (!ovf){
    for (int t = tid; t < total; t += TPB){
      int idx = bin_i[t];
      if (cmask[idx]){
        int sl = atomicAdd(&cnt2, 1);
        sv_u[sl] = bin_u[t]; sv_i[sl] = idx;  // sl < total <= BCAP <= TPB*SLOTS
      }
    }
  }
  __syncthreads();
  int S = cnt2;

  if (!ovf && S >= KTOP){
    // ---- FAST PATH (exact): all candidates with score>=THR are among the
    // survivors and S>=32 => true top-32 is a subset. Rank by (u desc, idx asc)
    // — matches the reference stable argsort tie-break.
    for (int jj = tid; jj < S; jj += TPB){
      unsigned long long kj = ((unsigned long long)sv_u[jj] << 32)
                            | (unsigned long long)(unsigned)(~(unsigned)sv_i[jj]);
      int rank = 0;
      for (int k = 0; k < S; ++k){
        unsigned long long kk = ((unsigned long long)sv_u[k] << 32)
                              | (unsigned long long)(unsigned)(~(unsigned)sv_i[k]);
        rank += (kk > kj) ? 1 : 0;
      }
      if (rank < KTOP){
        int sl = atomicAdd(&vcnt, 1);
        if (sl < KTOP) vidx[sl] = sv_i[jj];   // exactly KTOP ranks < KTOP
      }
    }
  } else {
    // ---- FALLBACK (exact, rare): full radix top-k with dense rescan ----
    int* hist = (int*)su;                     // alias (2048 ints <= 3072 slot words)
    auto scan_sc = [&](auto&& fn){
      int i = s + tid;  if (i < s4) fn(scores[i], i);
      int j = e4 + tid; if (j < e)  fn(scores[j], j);
      for (int q = (s4 >> 2) + tid, qe = (e4 >> 2); q < qe; q += TPB){
        float4 sc = sc4[q];
        int base = q << 2;
        fn(sc.x, base);     fn(sc.y, base + 1);
        fn(sc.z, base + 2); fn(sc.w, base + 3);
      }
    };
    auto is_cand = [&](int idx) -> bool { return cmask[idx] != 0; };

    for (int b = tid; b < 2048; b += TPB) hist[b] = 0;
    if (tid == 0){ scnt = 0; cnt_ab = 0; }
    __syncthreads();
    scan_sc([&](float sc, int idx){
      if (is_cand(idx)) atomicAdd(&hist[f2u(sc) >> 21], 1);
    });
    __syncthreads();
    int T = suffix_total(hist, 2048, gsum, tid);
    bool sel = (T > KTOP);
    unsigned int prefix = 0; int pshift = 32; int R = KTOP;
    if (sel){
      int above;
      int b1 = find_bin(hist, 2048, gsum, R, s2, tid, &above);
      R -= above; prefix = (unsigned)b1; pshift = 21;
      int hcnt = hist[b1];
      __syncthreads();
      if (hcnt > BCAP){                       // refine bits [20:10]
        for (int b = tid; b < 2048; b += TPB) hist[b] = 0;
        __syncthreads();
        scan_sc([&](float sc, int idx){
          unsigned u = f2u(sc);
          if ((u >> 21) == prefix && is_cand(idx))
            atomicAdd(&hist[(u >> 10) & 0x7FFu], 1);
        });
        __syncthreads();
        suffix_total(hist, 2048, gsum, tid);
        int b2 = find_bin(hist, 2048, gsum, R, s2, tid, &above);
        R -= above; prefix = (prefix << 11) | (unsigned)b2; pshift = 10;
        hcnt = hist[b2];
        __syncthreads();
        if (hcnt > BCAP){                     // final bits [9:0]
          for (int b = tid; b < 1024; b += TPB) hist[b] = 0;
          __syncthreads();
          scan_sc([&](float sc, int idx){
            unsigned u = f2u(sc);
            if ((u >> 10) == prefix && is_cand(idx))
              atomicAdd(&hist[u & 0x3FFu], 1);
          });
          __syncthreads();
          suffix_total(hist, 1024, gsum, tid);
          int b3 = find_bin(hist, 1024, gsum, R, s2, tid, &above);
          R -= above; prefix = (prefix << 10) | (unsigned)b3; pshift = 0;
          __syncthreads();
        }
      }
      scan_sc([&](float sc, int idx){
        unsigned u = f2u(sc);
        unsigned hp = (pshift < 32) ? (u >> pshift) : 0u;
        if (hp >= prefix){
          if (is_cand(idx)){
            if (hp == prefix){
              int sl = atomicAdd(&scnt, 1);
              if (sl < BCAP){ bin_u[sl] = u; bin_i[sl] = idx; }
            } else {
              int sl = atomicAdd(&cnt_ab, 1);
              if (sl < KTOP) ab_i[sl] = idx;  // strictly-above count < R <= 32
            }
          }
        }
      });
      __syncthreads();
      int bn = min(scnt, BCAP);
      for (int jj = tid; jj < bn; jj += TPB){
        unsigned long long kj = ((unsigned long long)bin_u[jj] << 32)
                              | (unsigned long long)(unsigned)(~(unsigned)bin_i[jj]);
        int rank = 0;
        for (int k = 0; k < bn; ++k){
          unsigned long long kk2 = ((unsigned long long)bin_u[k] << 32)
                                 | (unsigned long long)(unsigned)(~(unsigned)bin_i[k]);
          rank += (kk2 > kj) ? 1 : 0;
        }
        if (rank < R){
          int sl = atomicAdd(&vcnt, 1);
          if (sl < KTOP) vidx[sl] = bin_i[jj];
        }
      }
      int na = min(cnt_ab, KTOP);
      for (int jj = tid; jj < na; jj += TPB){
        int sl = atomicAdd(&vcnt, 1);
        if (sl < KTOP) vidx[sl] = ab_i[jj];
      }
    } else {
      // T <= 32: every candidate is valid
      scan_sc([&](float sc, int idx){
        (void)sc;
        if (is_cand(idx)){
          int sl = atomicAdd(&vcnt, 1);
          if (sl < KTOP) vidx[sl] = idx;
        }
      });
    }
  }
  __syncthreads();

  // ---- LSE over the <=32 valid logits (wave 0, shuffle-parallel) ----
  int c = min(vcnt, KTOP);
  if (tid < c) vlog[tid] = logits[vidx[tid]];
  __syncthreads();
  if (tid < 64){
    float v = (tid < c) ? vlog[tid] : -FLT_MAX;
    float m = v;
    #pragma unroll
    for (int d = 32; d; d >>= 1) m = fmaxf(m, __shfl_xor(m, d));
    float ex = (tid < c) ? expf(v - m) : 0.f;
    #pragma unroll
    for (int d = 32; d; d >>= 1) ex += __shfl_xor(ex, d);
    if (tid == 0){
      float stop = stop_logits[g];              // TEMP == 1.0
      float logden;
      if (c == 0){
        logden = stop;                          // logaddexp(~-inf, stop) = stop
      } else {
        float lse = logf(fmaxf(ex, FLT_EPSILON)) + m;   // eps clamp per reference
        float mx = fmaxf(lse, stop);
        float dd = fabsf(lse - stop);
        logden = mx + log1pf(expf(-dd));        // logaddexp(lse, stop)
      }
      sh_logden = logden;
    }
  }
  __syncthreads();

  // ---- scatter the <=32 valid log-probs over the sentinel fill ----
  if (tid < c){
    float val = vlog[tid] - sh_logden;
    if (!(val >= -VCLAMP)) val = -VCLAMP;       // flushes NaN too
    if (val > VCLAMP)      val =  VCLAMP;
    out[vidx[tid]] = val;
  }
}

extern "C" void kernel_launch(void* const* d_in, const int* in_sizes, int n_in,
                              void* d_out, int out_size, void* d_ws, size_t ws_size,
                              hipStream_t stream){
  const float* edge_logits = (const float*)d_in[0];
  const float* edge_scores = (const float*)d_in[1];
  const float* stop_logits = (const float*)d_in[2];
  const int*   edge_batch  = (const int*)d_in[3];
  const int*   cmask       = (const int*)d_in[4];
  int E  = in_sizes[0];
  int NG = in_sizes[2];
  float* out = (float*)d_out;
  (void)d_ws; (void)ws_size;   // ws poison costs ~41 us/iter -> avoid ws entirely

  hipLaunchKernelGGL(fused_kernel, dim3(NG), dim3(TPB), 0, stream,
                     edge_logits, edge_scores, stop_logits, edge_batch, cmask,
                     out, E, NG);
}